// Round 3
// baseline (473.557 us; speedup 1.0000x reference)
//
#include <hip/hip_runtime.h>
#include <stdint.h>

#define NN 8192
#define FIN 512
#define FOUT 256
#define ALPHA 0.2f
#define KSPLIT 4
#define KSLICE (NN / KSPLIT)   // 2048
#define BK 32

typedef float f32x4 __attribute__((ext_vector_type(4)));
typedef short s16x8 __attribute__((ext_vector_type(8)));
typedef short s16x4 __attribute__((ext_vector_type(4)));

__device__ __forceinline__ uint16_t f2bf(float f) {
  union { float f; uint32_t u; } v; v.f = f;
  uint32_t u = v.u + 0x7fffu + ((v.u >> 16) & 1u);
  return (uint16_t)(u >> 16);
}

// ---------------- 1. wa1/wa2 = W @ a1 / a2 (fp32) ----------------
__global__ __launch_bounds__(256) void k_wa(const float* __restrict__ W,
                                            const float* __restrict__ a,
                                            float* __restrict__ wa1, float* __restrict__ wa2) {
  __shared__ float a1[256], a2[256];
  int tid = threadIdx.x;
  a1[tid] = a[tid];
  a2[tid] = a[tid + 256];
  __syncthreads();
  int m = blockIdx.x * 256 + tid;   // 0..511
  const float* wrow = W + (size_t)m * FOUT;
  float s1 = 0.f, s2 = 0.f;
  for (int k = 0; k < FOUT; k += 4) {
    f32x4 v = *(const f32x4*)(wrow + k);
#pragma unroll
    for (int i = 0; i < 4; i++) {
      s1 += v[i] * a1[k + i];
      s2 += v[i] * a2[k + i];
    }
  }
  wa1[m] = s1; wa2[m] = s2;
}

// ---------------- 2. f1/f2 = x @ wa1/wa2 (fp32, one wave per row) ----------------
__global__ __launch_bounds__(256) void k_f1f2(const float* __restrict__ x,
                                              const float* __restrict__ wa1,
                                              const float* __restrict__ wa2,
                                              float* __restrict__ f1, float* __restrict__ f2) {
  __shared__ float s1[512], s2[512];
  int tid = threadIdx.x;
  s1[tid] = wa1[tid]; s1[tid + 256] = wa1[tid + 256];
  s2[tid] = wa2[tid]; s2[tid + 256] = wa2[tid + 256];
  __syncthreads();
  int w = tid >> 6, l = tid & 63;
  int row = blockIdx.x * 4 + w;
  const float* xr = x + (size_t)row * FIN + l * 8;
  f32x4 v0 = *(const f32x4*)xr;
  f32x4 v1 = *(const f32x4*)(xr + 4);
  int kb = l * 8;
  float d1 = 0.f, d2 = 0.f;
#pragma unroll
  for (int i = 0; i < 4; i++) {
    d1 += v0[i] * s1[kb + i] + v1[i] * s1[kb + 4 + i];
    d2 += v0[i] * s2[kb + i] + v1[i] * s2[kb + 4 + i];
  }
#pragma unroll
  for (int off = 32; off; off >>= 1) {
    d1 += __shfl_down(d1, off);
    d2 += __shfl_down(d2, off);
  }
  if (l == 0) { f1[row] = d1; f2[row] = d2; }
}

// ---------------- 3. wt[f][k] = bf16(W[k][f]) ----------------
__global__ __launch_bounds__(256) void k_prep_wt(const float* __restrict__ W,
                                                 uint16_t* __restrict__ wt) {
  int idx = blockIdx.x * 256 + threadIdx.x;   // 32768 threads, 4 elems each
  int f  = idx >> 7;                          // 0..255
  int k4 = (idx & 127) * 4;                   // 0..508
  ushort4 o;
  o.x = f2bf(W[(size_t)(k4 + 0) * FOUT + f]);
  o.y = f2bf(W[(size_t)(k4 + 1) * FOUT + f]);
  o.z = f2bf(W[(size_t)(k4 + 2) * FOUT + f]);
  o.w = f2bf(W[(size_t)(k4 + 3) * FOUT + f]);
  *(ushort4*)(wt + (size_t)f * FIN + k4) = o;
}

// ---------------- 4. ht = (x @ W)^T directly (bf16 MFMA, 512 thr) ----------------
// BM=64 rows, BN=256 (all features), BK=32. Wave w covers features w*32..w*32+31.
__global__ __launch_bounds__(512, 4) void k_gemm_h(const float* __restrict__ x,
                                                   const uint16_t* __restrict__ wt,
                                                   uint16_t* __restrict__ ht) {
  __shared__ __align__(16) uint16_t Xs[64][40];
  __shared__ __align__(16) uint16_t Ws[256][40];
  int i0 = blockIdx.x * 64;
  int tid = threadIdx.x;
  int l = tid & 63, w = tid >> 6;
  int q = l >> 4, r16 = l & 15;
  f32x4 acc[4][2];
#pragma unroll
  for (int a = 0; a < 4; a++)
#pragma unroll
    for (int b = 0; b < 2; b++) acc[a][b] = (f32x4)0.f;

  int xr = tid >> 3, xc = (tid & 7) * 4;     // x: 64x32 fp32, one f32x4/thread
  int wr = tid >> 1, wc = (tid & 1) * 16;    // wt: 256x32 bf16, 32B/thread
  const float* xp = x + (size_t)(i0 + xr) * FIN + xc;
  const uint16_t* wp = wt + (size_t)wr * FIN + wc;

  f32x4 xv = *(const f32x4*)xp;
  uint4 wA = *(const uint4*)wp;
  uint4 wB = *(const uint4*)(wp + 8);

  const int ITERS = FIN / BK;  // 16
  for (int s = 0; s < ITERS; s++) {
    int sn = (s + 1 < ITERS) ? (s + 1) : s;
    f32x4 xv2 = *(const f32x4*)(xp + sn * BK);
    uint4 wA2 = *(const uint4*)(wp + sn * BK);
    uint4 wB2 = *(const uint4*)(wp + sn * BK + 8);

    s16x4 xb;
#pragma unroll
    for (int i = 0; i < 4; i++) xb[i] = (short)f2bf(xv[i]);
    *(s16x4*)(&Xs[xr][xc]) = xb;
    *(uint4*)(&Ws[wr][wc]) = wA;
    *(uint4*)(&Ws[wr][wc + 8]) = wB;
    __syncthreads();

    s16x8 Af[4], Bf[2];
#pragma unroll
    for (int a = 0; a < 4; a++) Af[a] = *(const s16x8*)(&Xs[a * 16 + r16][q * 8]);
#pragma unroll
    for (int b = 0; b < 2; b++) Bf[b] = *(const s16x8*)(&Ws[w * 32 + b * 16 + r16][q * 8]);
#pragma unroll
    for (int a = 0; a < 4; a++)
#pragma unroll
      for (int b = 0; b < 2; b++)
        acc[a][b] = __builtin_amdgcn_mfma_f32_16x16x32_bf16(Af[a], Bf[b], acc[a][b], 0, 0, 0);
    __syncthreads();
    xv = xv2; wA = wA2; wB = wB2;
  }

  // epilogue: write ht[f][i]; lane's 4 regs are 4 consecutive rows -> 8B store
#pragma unroll
  for (int a = 0; a < 4; a++)
#pragma unroll
    for (int b = 0; b < 2; b++) {
      int f = w * 32 + b * 16 + r16;
      int i = i0 + a * 16 + q * 4;
      ushort4 o;
      o.x = f2bf(acc[a][b][0]); o.y = f2bf(acc[a][b][1]);
      o.z = f2bf(acc[a][b][2]); o.w = f2bf(acc[a][b][3]);
      *(ushort4*)(ht + (size_t)f * NN + i) = o;
    }
}

// ---------------- 5. zero the softmax denominators ----------------
__global__ __launch_bounds__(256) void k_zero(float* __restrict__ l_arr) {
  l_arr[blockIdx.x * 256 + threadIdx.x] = 0.f;
}

// ---------------- 6. fused scores -> P(bf16) -> P @ h (MFMA), split-K ----------------
// 512 threads (8 waves). BM=64, BN=256 (wave w -> features w*32..+31), BK=32.
// adj + ht staged with one-iteration register prefetch; f2 slice in LDS.
__global__ __launch_bounds__(512, 4) void k_att(const int* __restrict__ adj,
                                                const uint16_t* __restrict__ ht,
                                                const float* __restrict__ f1,
                                                const float* __restrict__ f2,
                                                float* __restrict__ l_arr,
                                                float* __restrict__ part) {
  __shared__ __align__(16) uint16_t Ps[64][40];
  __shared__ __align__(16) uint16_t Hs[256][40];
  __shared__ __align__(16) float Fs[KSLICE];     // 8 KB
  int i0 = blockIdx.x * 64;
  int jbase = blockIdx.y * KSLICE;
  int tid = threadIdx.x;
  int l = tid & 63, w = tid >> 6;
  int q = l >> 4, r16 = l & 15;
  int pr = tid >> 3, pc = tid & 7;      // P gen: 4 entries/thread
  int hr = tid >> 1, hc = (tid & 1) * 16;

  // stage f2 slice once
  *(f32x4*)(&Fs[tid * 4]) = *(const f32x4*)(f2 + jbase + tid * 4);

  float f1i = f1[i0 + pr];
  float lsum = 0.f;
  f32x4 acc[4][2];
#pragma unroll
  for (int a = 0; a < 4; a++)
#pragma unroll
    for (int b = 0; b < 2; b++) acc[a][b] = (f32x4)0.f;

  const int* adjp = adj + (size_t)(i0 + pr) * NN + jbase + pc * 4;
  const uint16_t* htp = ht + (size_t)hr * NN + jbase + hc;

  // prologue: loads for iter 0
  int4 adjR = *(const int4*)adjp;
  uint4 hA = *(const uint4*)htp;
  uint4 hB = *(const uint4*)(htp + 8);
  __syncthreads();   // Fs visible

  const int ITERS = KSLICE / BK;  // 64
  for (int s = 0; s < ITERS; s++) {
    int sn = (s + 1 < ITERS) ? (s + 1) : s;
    int4 adjN = *(const int4*)(adjp + (size_t)sn * BK);
    uint4 hA2 = *(const uint4*)(htp + sn * BK);
    uint4 hB2 = *(const uint4*)(htp + sn * BK + 8);

    // P tile from prefetched adj + LDS f2
    f32x4 F = *(const f32x4*)(&Fs[s * BK + pc * 4]);
    s16x4 pv;
#pragma unroll
    for (int i = 0; i < 4; i++) {
      float s_ = f1i + F[i];
      float e_ = fmaxf(s_, ALPHA * s_);          // LeakyReLU, alpha<1
      int av = (i == 0) ? adjR.x : (i == 1) ? adjR.y : (i == 2) ? adjR.z : adjR.w;
      float p_ = (av != 0) ? __expf(e_) : 1.0f;
      lsum += p_;
      pv[i] = (short)f2bf(p_);
    }
    *(s16x4*)(&Ps[pr][pc * 4]) = pv;
    *(uint4*)(&Hs[hr][hc]) = hA;
    *(uint4*)(&Hs[hr][hc + 8]) = hB;
    __syncthreads();

    s16x8 Af[4], Bf[2];
#pragma unroll
    for (int a = 0; a < 4; a++) Af[a] = *(const s16x8*)(&Ps[a * 16 + r16][q * 8]);
#pragma unroll
    for (int b = 0; b < 2; b++) Bf[b] = *(const s16x8*)(&Hs[w * 32 + b * 16 + r16][q * 8]);
#pragma unroll
    for (int a = 0; a < 4; a++)
#pragma unroll
      for (int b = 0; b < 2; b++)
        acc[a][b] = __builtin_amdgcn_mfma_f32_16x16x32_bf16(Af[a], Bf[b], acc[a][b], 0, 0, 0);
    __syncthreads();
    adjR = adjN; hA = hA2; hB = hB2;
  }

  // denominator: reduce over the 8 lanes sharing pr, one atomic per row
  lsum += __shfl_down(lsum, 4);
  lsum += __shfl_down(lsum, 2);
  lsum += __shfl_down(lsum, 1);
  if (pc == 0) atomicAdd(&l_arr[i0 + pr], lsum);

  float* pb = part + (size_t)blockIdx.y * ((size_t)NN * FOUT);
#pragma unroll
  for (int a = 0; a < 4; a++)
#pragma unroll
    for (int b = 0; b < 2; b++)
#pragma unroll
      for (int reg = 0; reg < 4; reg++) {
        int row = i0 + a * 16 + q * 4 + reg;
        int col = w * 32 + b * 16 + r16;
        pb[(size_t)row * FOUT + col] = acc[a][b][reg];
      }
}

// ---------------- 7. combine split-K partials, /l, ELU, fp32 out ----------------
__global__ __launch_bounds__(256) void k_combine(const float* __restrict__ part,
                                                 const float* __restrict__ l_arr,
                                                 float* __restrict__ out) {
  int idx = (blockIdx.x * 256 + threadIdx.x) * 4;
  float r = 1.0f / l_arr[idx >> 8];
  f32x4 v0 = *(const f32x4*)(part + 0 * (size_t)(NN * FOUT) + idx);
  f32x4 v1 = *(const f32x4*)(part + 1 * (size_t)(NN * FOUT) + idx);
  f32x4 v2 = *(const f32x4*)(part + 2 * (size_t)(NN * FOUT) + idx);
  f32x4 v3 = *(const f32x4*)(part + 3 * (size_t)(NN * FOUT) + idx);
  f32x4 o;
#pragma unroll
  for (int i = 0; i < 4; i++) {
    float v = (v0[i] + v1[i] + v2[i] + v3[i]) * r;
    o[i] = v > 0.f ? v : (__expf(v) - 1.f);
  }
  *(f32x4*)(out + idx) = o;
}

extern "C" void kernel_launch(void* const* d_in, const int* in_sizes, int n_in,
                              void* d_out, int out_size, void* d_ws, size_t ws_size,
                              hipStream_t stream) {
  const float* x   = (const float*)d_in[0];
  const int*   adj = (const int*)d_in[1];
  const float* W   = (const float*)d_in[2];
  const float* a   = (const float*)d_in[3];
  float* out = (float*)d_out;

  char* ws = (char*)d_ws;
  float*    wa1   = (float*)ws;                        // 512 f32
  float*    wa2   = wa1 + 512;                         // 512 f32
  float*    f1    = wa2 + 512;                         // 8192 f32
  float*    f2    = f1 + NN;                           // 8192 f32
  float*    l_arr = f2 + NN;                           // 8192 f32
  uint16_t* wt    = (uint16_t*)(l_arr + NN);           // 256*512 bf16 (256 KB)
  uint16_t* ht    = wt + (size_t)FOUT * FIN;           // 256*8192 bf16 (4 MB)
  float*    part  = (float*)(ht + (size_t)NN * FOUT);  // KSPLIT * 8192*256 f32 (32 MB)

  k_wa<<<2, 256, 0, stream>>>(W, a, wa1, wa2);
  k_f1f2<<<NN / 4, 256, 0, stream>>>(x, wa1, wa2, f1, f2);
  k_prep_wt<<<128, 256, 0, stream>>>(W, wt);
  k_gemm_h<<<128, 512, 0, stream>>>(x, wt, ht);
  k_zero<<<NN / 256, 256, 0, stream>>>(l_arr);
  k_att<<<dim3(NN / 64, KSPLIT), 512, 0, stream>>>(adj, ht, f1, f2, l_arr, part);
  k_combine<<<NN * FOUT / 1024, 256, 0, stream>>>(part, l_arr, out);
}